// Round 1
// baseline (883.435 us; speedup 1.0000x reference)
//
#include <hip/hip_runtime.h>
#include <hip/hip_bf16.h>
#include <stdint.h>

// BitNet MNIST MLP: 3x {absmean-ternary bitlinear} with rmsnorm+gelu between.
// Round 0: bf16 MFMA 128x128 tiles, reg-staging, unfused norm, bf16 intermediates.
// x_scale cancels mathematically (out = (x/s)@Wq^T * s == x@Wq^T), so activations
// are only bf16-rounded, never quantized.

typedef __attribute__((ext_vector_type(8))) short short8;
typedef __attribute__((ext_vector_type(4))) float f32x4;

#define B_TOTAL 65536
#define IN_DIM 784
#define IN_PAD 800
#define H_DIM 1024
#define OUT_DIM 10
#define OUT_PAD 16

__device__ __forceinline__ unsigned short f2bf(float f) {
    union { float f; unsigned u; } c; c.f = f;
    unsigned r = c.u + 0x7FFFu + ((c.u >> 16) & 1u);
    return (unsigned short)(r >> 16);
}
__device__ __forceinline__ float bf2f(unsigned short h) {
    union { unsigned u; float f; } c; c.u = ((unsigned)h) << 16;
    return c.f;
}

// ---------- weight |w| sum (double atomic: deterministic to ~1e-15 rel) ----------
__global__ void absum_kernel(const float* __restrict__ w, int n, double* acc) {
    __shared__ float red[4];
    float s = 0.f;
    for (int i = blockIdx.x * blockDim.x + threadIdx.x; i < n; i += gridDim.x * blockDim.x)
        s += fabsf(w[i]);
#pragma unroll
    for (int o = 32; o > 0; o >>= 1) s += __shfl_xor(s, o);
    if ((threadIdx.x & 63) == 0) red[threadIdx.x >> 6] = s;
    __syncthreads();
    if (threadIdx.x == 0) {
        float t = red[0] + red[1] + red[2] + red[3];
        atomicAdd(acc, (double)t);
    }
}

// ---------- ternary quantize -> bf16, pad K to Kp and O rows to grid.y ----------
__global__ void quant_kernel(const float* __restrict__ w, unsigned short* __restrict__ wq,
                             int O, int K, int Kp, const double* sum, int n) {
    int k = blockIdx.x * blockDim.x + threadIdx.x;
    int o = blockIdx.y;
    if (k >= Kp) return;
    float scale = fmaxf((float)(*sum / (double)n), 1e-5f);
    float q = 0.f;
    if (o < O && k < K) {
        float r = rintf(w[(size_t)o * K + k] / scale);  // round-half-even, matches jnp.round
        q = fminf(1.f, fmaxf(-1.f, r));
    }
    wq[(size_t)o * Kp + k] = f2bf(q);
}

// ---------- GEMM: C[M x N] = A[M x K] * Bq[N x K]^T, bf16 MFMA 16x16x32 ----------
// 128x128 tile, 4 waves (2x2), BK=32, LDS padded [128][40] (2-way conflicts = free).
// AF32: A is fp32 (layer 1 input x), converted to bf16 during staging; K guard pads zeros.
template<bool AF32>
__global__ __launch_bounds__(256)
void gemm_nt(const void* __restrict__ A_, const unsigned short* __restrict__ Bq,
             unsigned short* __restrict__ C, int N, int K, int Kp, int lda) {
    __shared__ unsigned short As[128][40];
    __shared__ unsigned short Bs[128][40];
    const int tid = threadIdx.x;
    const int lane = tid & 63;
    const int wid = tid >> 6;
    const int wr = wid >> 1, wc = wid & 1;
    const int m0 = blockIdx.y * 128, n0 = blockIdx.x * 128;
    const int lr = lane & 15;
    const int lk = (lane >> 4) * 8;
    const int sr = tid >> 2;           // staging row within 64-row half
    const int sc = (tid & 3) * 8;      // staging col (8 consecutive k)
    f32x4 acc[4][4] = {};
    const int KT = Kp / 32;
    for (int kt = 0; kt < KT; ++kt) {
        const int gk = kt * 32 + sc;
        __syncthreads();
#pragma unroll
        for (int p = 0; p < 2; ++p) {
            const int r = p * 64 + sr;
            short8 av = 0;
            if (gk < K) {
                if constexpr (AF32) {
                    const float* Ap = (const float*)A_ + (size_t)(m0 + r) * lda + gk;
                    float4 f0 = *(const float4*)Ap;
                    float4 f1 = *(const float4*)(Ap + 4);
                    av[0] = (short)f2bf(f0.x); av[1] = (short)f2bf(f0.y);
                    av[2] = (short)f2bf(f0.z); av[3] = (short)f2bf(f0.w);
                    av[4] = (short)f2bf(f1.x); av[5] = (short)f2bf(f1.y);
                    av[6] = (short)f2bf(f1.z); av[7] = (short)f2bf(f1.w);
                } else {
                    av = *(const short8*)((const unsigned short*)A_ + (size_t)(m0 + r) * lda + gk);
                }
            }
            *(short8*)&As[r][sc] = av;
            // B rows are always valid (weights pre-padded to Kp)
            *(short8*)&Bs[r][sc] = *(const short8*)(Bq + (size_t)(n0 + r) * Kp + gk);
        }
        __syncthreads();
        short8 af[4], bfr[4];
#pragma unroll
        for (int m = 0; m < 4; ++m) af[m] = *(const short8*)&As[wr * 64 + m * 16 + lr][lk];
#pragma unroll
        for (int n = 0; n < 4; ++n) bfr[n] = *(const short8*)&Bs[wc * 64 + n * 16 + lr][lk];
#pragma unroll
        for (int m = 0; m < 4; ++m)
#pragma unroll
            for (int n = 0; n < 4; ++n)
                acc[m][n] = __builtin_amdgcn_mfma_f32_16x16x32_bf16(af[m], bfr[n], acc[m][n], 0, 0, 0);
    }
    // epilogue: C/D layout col=lane&15, row=(lane>>4)*4+j (HW-verified)
#pragma unroll
    for (int m = 0; m < 4; ++m)
#pragma unroll
        for (int n = 0; n < 4; ++n) {
            const int gcol = n0 + wc * 64 + n * 16 + lr;
            unsigned short* Cp = C + (size_t)(m0 + wr * 64 + m * 16 + (lane >> 4) * 4) * N + gcol;
#pragma unroll
            for (int j = 0; j < 4; ++j) Cp[(size_t)j * N] = f2bf(acc[m][n][j]);
        }
}

// ---------- rmsnorm + exact gelu, one wave per 1024-wide row ----------
__global__ __launch_bounds__(256)
void norm_gelu(const unsigned short* __restrict__ Hp, const float* __restrict__ g,
               unsigned short* __restrict__ U) {
    const int row = blockIdx.x * 4 + (threadIdx.x >> 6);
    const int lane = threadIdx.x & 63;
    const unsigned short* rp = Hp + (size_t)row * H_DIM;
    short8 v0 = *(const short8*)(rp + lane * 8);
    short8 v1 = *(const short8*)(rp + 512 + lane * 8);
    float f[16];
#pragma unroll
    for (int j = 0; j < 8; ++j) {
        f[j] = bf2f((unsigned short)v0[j]);
        f[8 + j] = bf2f((unsigned short)v1[j]);
    }
    float s = 0.f;
#pragma unroll
    for (int j = 0; j < 16; ++j) s += f[j] * f[j];
#pragma unroll
    for (int o = 32; o > 0; o >>= 1) s += __shfl_xor(s, o);
    const float rinv = 1.f / sqrtf(s * (1.f / 1024.f) + 1e-6f);
    short8 o0, o1;
#pragma unroll
    for (int j = 0; j < 8; ++j) {
        const int c0 = lane * 8 + j, c1 = 512 + lane * 8 + j;
        float t0 = f[j] * rinv * g[c0];
        float t1 = f[8 + j] * rinv * g[c1];
        float u0 = 0.5f * t0 * (1.f + erff(t0 * 0.70710678118f));
        float u1 = 0.5f * t1 * (1.f + erff(t1 * 0.70710678118f));
        o0[j] = (short)f2bf(u0);
        o1[j] = (short)f2bf(u1);
    }
    unsigned short* up = U + (size_t)row * H_DIM;
    *(short8*)(up + lane * 8) = o0;
    *(short8*)(up + 512 + lane * 8) = o1;
}

// ---------- final layer: out[M x 10] = A[M x 1024] * w3q[16 x 1024]^T ----------
__global__ __launch_bounds__(256)
void gemm3_kernel(const unsigned short* __restrict__ A, const unsigned short* __restrict__ Bq,
                  float* __restrict__ out) {
    __shared__ unsigned short As[128][40];
    __shared__ unsigned short Bs[16][40];
    const int tid = threadIdx.x;
    const int lane = tid & 63;
    const int wid = tid >> 6;
    const int m0 = blockIdx.x * 128;
    const int lr = lane & 15;
    const int lk = (lane >> 4) * 8;
    const int sr = tid >> 2;
    const int sc = (tid & 3) * 8;
    f32x4 acc[2] = {};
    for (int kt = 0; kt < 32; ++kt) {
        const int kb = kt * 32;
        __syncthreads();
#pragma unroll
        for (int p = 0; p < 2; ++p) {
            const int r = p * 64 + sr;
            *(short8*)&As[r][sc] = *(const short8*)(A + (size_t)(m0 + r) * H_DIM + kb + sc);
        }
        if (tid < 64) {
            const int r = tid >> 2;
            const int c = (tid & 3) * 8;
            *(short8*)&Bs[r][c] = *(const short8*)(Bq + (size_t)r * H_DIM + kb + c);
        }
        __syncthreads();
        short8 bv = *(const short8*)&Bs[lr][lk];
#pragma unroll
        for (int m = 0; m < 2; ++m) {
            short8 a = *(const short8*)&As[wid * 32 + m * 16 + lr][lk];
            acc[m] = __builtin_amdgcn_mfma_f32_16x16x32_bf16(a, bv, acc[m], 0, 0, 0);
        }
    }
    if (lr < OUT_DIM) {
#pragma unroll
        for (int m = 0; m < 2; ++m)
#pragma unroll
            for (int j = 0; j < 4; ++j) {
                const int grow = m0 + wid * 32 + m * 16 + (lane >> 4) * 4 + j;
                out[(size_t)grow * OUT_DIM + lr] = acc[m][j];
            }
    }
}

extern "C" void kernel_launch(void* const* d_in, const int* in_sizes, int n_in,
                              void* d_out, int out_size, void* d_ws, size_t ws_size,
                              hipStream_t stream) {
    (void)in_sizes; (void)n_in; (void)out_size;
    const float* x  = (const float*)d_in[0];
    const float* w1 = (const float*)d_in[1];
    const float* g1 = (const float*)d_in[2];
    const float* w2 = (const float*)d_in[3];
    const float* g2 = (const float*)d_in[4];
    const float* w3 = (const float*)d_in[5];
    float* out = (float*)d_out;

    uint8_t* ws = (uint8_t*)d_ws;
    double* sums = (double*)ws;
    size_t off = 256;
    unsigned short* w1q = (unsigned short*)(ws + off); off += (size_t)H_DIM * IN_PAD * 2;
    unsigned short* w2q = (unsigned short*)(ws + off); off += (size_t)H_DIM * H_DIM * 2;
    unsigned short* w3q = (unsigned short*)(ws + off); off += (size_t)OUT_PAD * H_DIM * 2;

    // pick largest batch chunk R whose two bf16 [R x 1024] buffers fit in ws
    size_t rem = (ws_size > off) ? ws_size - off : 0;
    int R = B_TOTAL;
    while (R > 1024 && (size_t)2 * R * H_DIM * 2 > rem) R >>= 1;
    unsigned short* bufA = (unsigned short*)(ws + off);
    unsigned short* bufB = bufA + (size_t)R * H_DIM;

    hipMemsetAsync(sums, 0, 3 * sizeof(double), stream);
    absum_kernel<<<128, 256, 0, stream>>>(w1, H_DIM * IN_DIM, sums + 0);
    absum_kernel<<<128, 256, 0, stream>>>(w2, H_DIM * H_DIM, sums + 1);
    absum_kernel<<<128, 256, 0, stream>>>(w3, OUT_DIM * H_DIM, sums + 2);
    quant_kernel<<<dim3((IN_PAD + 255) / 256, H_DIM), 256, 0, stream>>>(
        w1, w1q, H_DIM, IN_DIM, IN_PAD, sums + 0, H_DIM * IN_DIM);
    quant_kernel<<<dim3((H_DIM + 255) / 256, H_DIM), 256, 0, stream>>>(
        w2, w2q, H_DIM, H_DIM, H_DIM, sums + 1, H_DIM * H_DIM);
    quant_kernel<<<dim3((H_DIM + 255) / 256, OUT_PAD), 256, 0, stream>>>(
        w3, w3q, OUT_DIM, H_DIM, H_DIM, sums + 2, OUT_DIM * H_DIM);

    const int nchunk = B_TOTAL / R;
    for (int c = 0; c < nchunk; ++c) {
        const float* xc = x + (size_t)c * R * IN_DIM;
        gemm_nt<true><<<dim3(H_DIM / 128, R / 128), 256, 0, stream>>>(
            xc, w1q, bufA, H_DIM, IN_DIM, IN_PAD, IN_DIM);
        norm_gelu<<<R / 4, 256, 0, stream>>>(bufA, g1, bufB);
        gemm_nt<false><<<dim3(H_DIM / 128, R / 128), 256, 0, stream>>>(
            bufB, w2q, bufA, H_DIM, H_DIM, H_DIM, H_DIM);
        norm_gelu<<<R / 4, 256, 0, stream>>>(bufA, g2, bufB);
        gemm3_kernel<<<R / 128, 256, 0, stream>>>(bufB, w3q, out + (size_t)c * R * OUT_DIM);
    }
}

// Round 2
// 696.805 us; speedup vs baseline: 1.2678x; 1.2678x over previous
//
#include <hip/hip_runtime.h>
#include <hip/hip_bf16.h>
#include <stdint.h>

// BitNet MNIST MLP, Round 1: m97-structure GEMM (global_load_lds w=16, linear LDS,
// 128x128 tile, BK=32) + XCD-grouped block swizzle. x pre-converted fp32->bf16 (pad 800).
// x_scale cancels mathematically; weights ternary-quantized once per call (double atomics).

typedef __attribute__((ext_vector_type(8))) short short8;
typedef __attribute__((ext_vector_type(4))) float f32x4;

#define B_TOTAL 65536
#define IN_DIM 784
#define IN_PAD 800
#define H_DIM 1024
#define OUT_DIM 10
#define OUT_PAD 16

__device__ __forceinline__ unsigned short f2bf(float f) {
    union { float f; unsigned u; } c; c.f = f;
    unsigned r = c.u + 0x7FFFu + ((c.u >> 16) & 1u);
    return (unsigned short)(r >> 16);
}
__device__ __forceinline__ float bf2f(unsigned short h) {
    union { unsigned u; float f; } c; c.u = ((unsigned)h) << 16;
    return c.f;
}

#define GLOAD16(gp, lp)                                                        \
    __builtin_amdgcn_global_load_lds(                                          \
        (const __attribute__((address_space(1))) void*)(gp),                   \
        (__attribute__((address_space(3))) void*)(lp), 16, 0, 0)

// ---------- weight |w| sum (double atomic: deterministic) ----------
__global__ void absum_kernel(const float* __restrict__ w, int n, double* acc) {
    __shared__ float red[4];
    float s = 0.f;
    for (int i = blockIdx.x * blockDim.x + threadIdx.x; i < n; i += gridDim.x * blockDim.x)
        s += fabsf(w[i]);
#pragma unroll
    for (int o = 32; o > 0; o >>= 1) s += __shfl_xor(s, o);
    if ((threadIdx.x & 63) == 0) red[threadIdx.x >> 6] = s;
    __syncthreads();
    if (threadIdx.x == 0) {
        float t = red[0] + red[1] + red[2] + red[3];
        atomicAdd(acc, (double)t);
    }
}

// ---------- ternary quantize -> bf16, pad K to Kp and O rows up ----------
__global__ void quant_kernel(const float* __restrict__ w, unsigned short* __restrict__ wq,
                             int O, int K, int Kp, const double* sum, int n) {
    int k = blockIdx.x * blockDim.x + threadIdx.x;
    int o = blockIdx.y;
    if (k >= Kp) return;
    float scale = fmaxf((float)(*sum / (double)n), 1e-5f);
    float q = 0.f;
    if (o < O && k < K) {
        float r = rintf(w[(size_t)o * K + k] / scale);  // round-half-even == jnp.round
        q = fminf(1.f, fmaxf(-1.f, r));
    }
    wq[(size_t)o * Kp + k] = f2bf(q);
}

// ---------- x fp32 [R x 784] -> bf16 [R x 800] (zero-padded) ----------
__global__ __launch_bounds__(256)
void convert_pad(const float* __restrict__ x, unsigned short* __restrict__ xb) {
    const int g = blockIdx.x * 256 + threadIdx.x;   // one 8-col group per thread
    const int row = g / 100;
    const int c = (g % 100) * 8;
    short8 v = 0;
    if (c < IN_DIM) {
        const float* p = x + (size_t)row * IN_DIM + c;
        float4 f0 = *(const float4*)p;
        float4 f1 = *(const float4*)(p + 4);
        v[0] = (short)f2bf(f0.x); v[1] = (short)f2bf(f0.y);
        v[2] = (short)f2bf(f0.z); v[3] = (short)f2bf(f0.w);
        v[4] = (short)f2bf(f1.x); v[5] = (short)f2bf(f1.y);
        v[6] = (short)f2bf(f1.z); v[7] = (short)f2bf(f1.w);
    }
    *(short8*)(xb + (size_t)row * IN_PAD + c) = v;
}

// ---------- GEMM: C[M x 1024] = A[M x KP] * Bq[1024 x KP]^T, bf16 MFMA ----------
// m97 structure: 128x128 tile, 4 waves (2x2), BK=32, global_load_lds width-16,
// linear LDS [128][32] per operand. XCD-grouped 1-D grid: all 8 n-blocks of an
// m-panel run consecutively on one XCD -> A-panel L2-resident.
template<int KP>
__global__ __launch_bounds__(256)
void gemm_bt(const unsigned short* __restrict__ A, const unsigned short* __restrict__ Bq,
             unsigned short* __restrict__ C) {
    __shared__ __attribute__((aligned(16))) unsigned short As[128 * 32];
    __shared__ __attribute__((aligned(16))) unsigned short Bs[128 * 32];
    const int tid = threadIdx.x;
    const int lane = tid & 63;
    const int wid = tid >> 6;
    const int wr = wid >> 1, wc = wid & 1;
    // XCD-grouped bijective mapping (grid = M_BLKS*8, M_BLKS % 8 == 0)
    const int bid = blockIdx.x;
    const int xcd = bid & 7;
    const int slot = bid >> 3;
    const int n_blk = slot & 7;
    const int m_blk = xcd * (gridDim.x >> 6) + (slot >> 3);
    const int m0 = m_blk * 128, n0 = n_blk * 128;
    const int lr = lane & 15;
    const int lk = (lane >> 4) * 8;
    const int srow = lane >> 2;        // 0..15 (16 rows per wave-load)
    const int scol = (lane & 3) * 8;   // 8 consecutive k per lane (16 B)
    // per-wave staging: wave w owns rows [32w, 32w+32) of both tiles
    const unsigned short* ga = A + (size_t)(m0 + wid * 32 + srow) * KP + scol;
    const unsigned short* gb = Bq + (size_t)(n0 + wid * 32 + srow) * KP + scol;
    unsigned short* la = &As[wid * 1024];   // wave-uniform LDS base
    unsigned short* lb = &Bs[wid * 1024];
    f32x4 acc[4][4] = {};
    for (int kt = 0; kt < KP / 32; ++kt) {
        GLOAD16(ga, la);
        GLOAD16(ga + 16 * KP, la + 512);
        GLOAD16(gb, lb);
        GLOAD16(gb + 16 * KP, lb + 512);
        ga += 32; gb += 32;
        __syncthreads();   // vmcnt(0) drained -> tiles ready
        short8 af[4], bfr[4];
#pragma unroll
        for (int m = 0; m < 4; ++m)
            af[m] = *(const short8*)&As[(wr * 64 + m * 16 + lr) * 32 + lk];
#pragma unroll
        for (int n = 0; n < 4; ++n)
            bfr[n] = *(const short8*)&Bs[(wc * 64 + n * 16 + lr) * 32 + lk];
#pragma unroll
        for (int m = 0; m < 4; ++m)
#pragma unroll
            for (int n = 0; n < 4; ++n)
                acc[m][n] = __builtin_amdgcn_mfma_f32_16x16x32_bf16(af[m], bfr[n], acc[m][n], 0, 0, 0);
        __syncthreads();   // all reads done before next-iter overwrite
    }
    // epilogue: C/D layout col=lane&15, row=(lane>>4)*4+j (HW-verified)
#pragma unroll
    for (int m = 0; m < 4; ++m)
#pragma unroll
        for (int n = 0; n < 4; ++n) {
            const int gcol = n0 + wc * 64 + n * 16 + lr;
            unsigned short* Cp = C + (size_t)(m0 + wr * 64 + m * 16 + (lane >> 4) * 4) * H_DIM + gcol;
#pragma unroll
            for (int j = 0; j < 4; ++j) Cp[(size_t)j * H_DIM] = f2bf(acc[m][n][j]);
        }
}

// ---------- rmsnorm + exact gelu, one wave per 1024-wide row ----------
__global__ __launch_bounds__(256)
void norm_gelu(const unsigned short* __restrict__ Hp, const float* __restrict__ g,
               unsigned short* __restrict__ U) {
    const int row = blockIdx.x * 4 + (threadIdx.x >> 6);
    const int lane = threadIdx.x & 63;
    const unsigned short* rp = Hp + (size_t)row * H_DIM;
    short8 v0 = *(const short8*)(rp + lane * 8);
    short8 v1 = *(const short8*)(rp + 512 + lane * 8);
    float f[16];
#pragma unroll
    for (int j = 0; j < 8; ++j) {
        f[j] = bf2f((unsigned short)v0[j]);
        f[8 + j] = bf2f((unsigned short)v1[j]);
    }
    float s = 0.f;
#pragma unroll
    for (int j = 0; j < 16; ++j) s += f[j] * f[j];
#pragma unroll
    for (int o = 32; o > 0; o >>= 1) s += __shfl_xor(s, o);
    const float rinv = 1.f / sqrtf(s * (1.f / 1024.f) + 1e-6f);
    short8 o0, o1;
#pragma unroll
    for (int j = 0; j < 8; ++j) {
        const int c0 = lane * 8 + j, c1 = 512 + lane * 8 + j;
        float t0 = f[j] * rinv * g[c0];
        float t1 = f[8 + j] * rinv * g[c1];
        float u0 = 0.5f * t0 * (1.f + erff(t0 * 0.70710678118f));
        float u1 = 0.5f * t1 * (1.f + erff(t1 * 0.70710678118f));
        o0[j] = (short)f2bf(u0);
        o1[j] = (short)f2bf(u1);
    }
    unsigned short* up = U + (size_t)row * H_DIM;
    *(short8*)(up + lane * 8) = o0;
    *(short8*)(up + 512 + lane * 8) = o1;
}

// ---------- final layer: out[M x 10] = A[M x 1024] * w3q[16 x 1024]^T ----------
__global__ __launch_bounds__(256)
void gemm3_kernel(const unsigned short* __restrict__ A, const unsigned short* __restrict__ Bq,
                  float* __restrict__ out) {
    __shared__ unsigned short As[128][40];
    __shared__ unsigned short Bs[16][40];
    const int tid = threadIdx.x;
    const int lane = tid & 63;
    const int wid = tid >> 6;
    const int m0 = blockIdx.x * 128;
    const int lr = lane & 15;
    const int lk = (lane >> 4) * 8;
    const int sr = tid >> 2;
    const int sc = (tid & 3) * 8;
    f32x4 acc[2] = {};
    for (int kt = 0; kt < 32; ++kt) {
        const int kb = kt * 32;
        __syncthreads();
#pragma unroll
        for (int p = 0; p < 2; ++p) {
            const int r = p * 64 + sr;
            *(short8*)&As[r][sc] = *(const short8*)(A + (size_t)(m0 + r) * H_DIM + kb + sc);
        }
        if (tid < 64) {
            const int r = tid >> 2;
            const int c = (tid & 3) * 8;
            *(short8*)&Bs[r][c] = *(const short8*)(Bq + (size_t)r * H_DIM + kb + c);
        }
        __syncthreads();
        short8 bv = *(const short8*)&Bs[lr][lk];
#pragma unroll
        for (int m = 0; m < 2; ++m) {
            short8 a = *(const short8*)&As[wid * 32 + m * 16 + lr][lk];
            acc[m] = __builtin_amdgcn_mfma_f32_16x16x32_bf16(a, bv, acc[m], 0, 0, 0);
        }
    }
    if (lr < OUT_DIM) {
#pragma unroll
        for (int m = 0; m < 2; ++m)
#pragma unroll
            for (int j = 0; j < 4; ++j) {
                const int grow = m0 + wid * 32 + m * 16 + (lane >> 4) * 4 + j;
                out[(size_t)grow * OUT_DIM + lr] = acc[m][j];
            }
    }
}

extern "C" void kernel_launch(void* const* d_in, const int* in_sizes, int n_in,
                              void* d_out, int out_size, void* d_ws, size_t ws_size,
                              hipStream_t stream) {
    (void)in_sizes; (void)n_in; (void)out_size;
    const float* x  = (const float*)d_in[0];
    const float* w1 = (const float*)d_in[1];
    const float* g1 = (const float*)d_in[2];
    const float* w2 = (const float*)d_in[3];
    const float* g2 = (const float*)d_in[4];
    const float* w3 = (const float*)d_in[5];
    float* out = (float*)d_out;

    uint8_t* ws = (uint8_t*)d_ws;
    double* sums = (double*)ws;
    size_t off = 256;
    unsigned short* w1q = (unsigned short*)(ws + off); off += (size_t)H_DIM * IN_PAD * 2;
    unsigned short* w2q = (unsigned short*)(ws + off); off += (size_t)H_DIM * H_DIM * 2;
    unsigned short* w3q = (unsigned short*)(ws + off); off += (size_t)OUT_PAD * H_DIM * 2;

    // largest pow2 chunk R whose two bf16 [R x 1024] buffers fit (bufB doubles as
    // the bf16 x-chunk [R x 800]: dead after GEMM1, first rewritten by norm1)
    size_t rem = (ws_size > off) ? ws_size - off : 0;
    int R = B_TOTAL;
    while (R > 1024 && (size_t)2 * R * H_DIM * 2 > rem) R >>= 1;
    unsigned short* bufA = (unsigned short*)(ws + off);
    unsigned short* bufB = bufA + (size_t)R * H_DIM;

    hipMemsetAsync(sums, 0, 3 * sizeof(double), stream);
    absum_kernel<<<128, 256, 0, stream>>>(w1, H_DIM * IN_DIM, sums + 0);
    absum_kernel<<<128, 256, 0, stream>>>(w2, H_DIM * H_DIM, sums + 1);
    absum_kernel<<<128, 256, 0, stream>>>(w3, OUT_DIM * H_DIM, sums + 2);
    quant_kernel<<<dim3((IN_PAD + 255) / 256, H_DIM), 256, 0, stream>>>(
        w1, w1q, H_DIM, IN_DIM, IN_PAD, sums + 0, H_DIM * IN_DIM);
    quant_kernel<<<dim3((H_DIM + 255) / 256, H_DIM), 256, 0, stream>>>(
        w2, w2q, H_DIM, H_DIM, H_DIM, sums + 1, H_DIM * H_DIM);
    quant_kernel<<<dim3((H_DIM + 255) / 256, OUT_PAD), 256, 0, stream>>>(
        w3, w3q, OUT_DIM, H_DIM, H_DIM, sums + 2, OUT_DIM * H_DIM);

    const int nchunk = B_TOTAL / R;
    for (int c = 0; c < nchunk; ++c) {
        const float* xc = x + (size_t)c * R * IN_DIM;
        convert_pad<<<R * 100 / 256, 256, 0, stream>>>(xc, bufB);
        gemm_bt<IN_PAD><<<(R / 128) * 8, 256, 0, stream>>>(bufB, w1q, bufA);
        norm_gelu<<<R / 4, 256, 0, stream>>>(bufA, g1, bufB);
        gemm_bt<H_DIM><<<(R / 128) * 8, 256, 0, stream>>>(bufB, w2q, bufA);
        norm_gelu<<<R / 4, 256, 0, stream>>>(bufA, g2, bufB);
        gemm3_kernel<<<R / 128, 256, 0, stream>>>(bufB, w3q, out + (size_t)c * R * OUT_DIM);
    }
}

// Round 3
// 631.778 us; speedup vs baseline: 1.3983x; 1.1029x over previous
//
#include <hip/hip_runtime.h>
#include <hip/hip_bf16.h>
#include <stdint.h>

// BitNet MNIST MLP, Round 2: 256x256 4-phase-per-K-tile pipelined GEMM
// (T2 st_16x32 swizzle + T3/T4 counted vmcnt + T5 setprio), 8 waves, BK=64,
// 2-K-tile LDS ring (128 KB), raw s_barrier (no vmcnt(0) drain).
// x_scale cancels mathematically; weights ternary-quantized once per call.

typedef __attribute__((ext_vector_type(8))) short short8;
typedef __attribute__((ext_vector_type(4))) float f32x4;

#define B_TOTAL 65536
#define IN_DIM 784
#define IN_PAD 896
#define H_DIM 1024
#define OUT_DIM 10
#define OUT_PAD 16

__device__ __forceinline__ unsigned short f2bf(float f) {
    union { float f; unsigned u; } c; c.f = f;
    unsigned r = c.u + 0x7FFFu + ((c.u >> 16) & 1u);
    return (unsigned short)(r >> 16);
}
__device__ __forceinline__ float bf2f(unsigned short h) {
    union { unsigned u; float f; } c; c.u = ((unsigned)h) << 16;
    return c.f;
}

#define GLOAD16(gp, lp)                                                        \
    __builtin_amdgcn_global_load_lds(                                          \
        (const __attribute__((address_space(1))) void*)(gp),                   \
        (__attribute__((address_space(3))) void*)(lp), 16, 0, 0)

#define BAR()                                                                  \
    {   __builtin_amdgcn_sched_barrier(0);                                     \
        __builtin_amdgcn_s_barrier();                                          \
        __builtin_amdgcn_sched_barrier(0); }

// ---------- weight |w| sum (double atomic: deterministic) ----------
__global__ void absum_kernel(const float* __restrict__ w, int n, double* acc) {
    __shared__ float red[4];
    float s = 0.f;
    for (int i = blockIdx.x * blockDim.x + threadIdx.x; i < n; i += gridDim.x * blockDim.x)
        s += fabsf(w[i]);
#pragma unroll
    for (int o = 32; o > 0; o >>= 1) s += __shfl_xor(s, o);
    if ((threadIdx.x & 63) == 0) red[threadIdx.x >> 6] = s;
    __syncthreads();
    if (threadIdx.x == 0) {
        float t = red[0] + red[1] + red[2] + red[3];
        atomicAdd(acc, (double)t);
    }
}

// ---------- ternary quantize -> bf16, pad K to Kp and O rows up ----------
__global__ void quant_kernel(const float* __restrict__ w, unsigned short* __restrict__ wq,
                             int O, int K, int Kp, const double* sum, int n) {
    int k = blockIdx.x * blockDim.x + threadIdx.x;
    int o = blockIdx.y;
    if (k >= Kp) return;
    float scale = fmaxf((float)(*sum / (double)n), 1e-5f);
    float q = 0.f;
    if (o < O && k < K) {
        float r = rintf(w[(size_t)o * K + k] / scale);  // round-half-even == jnp.round
        q = fminf(1.f, fmaxf(-1.f, r));
    }
    wq[(size_t)o * Kp + k] = f2bf(q);
}

// ---------- x fp32 [R x 784] -> bf16 [R x 896] (zero-padded) ----------
__global__ __launch_bounds__(256)
void convert_pad(const float* __restrict__ x, unsigned short* __restrict__ xb) {
    const int g = blockIdx.x * 256 + threadIdx.x;   // one 8-col group per thread
    const int row = g / 112;
    const int c = (g % 112) * 8;
    short8 v = 0;
    if (c < IN_DIM) {
        const float* p = x + (size_t)row * IN_DIM + c;
        float4 f0 = *(const float4*)p;
        float4 f1 = *(const float4*)(p + 4);
        v[0] = (short)f2bf(f0.x); v[1] = (short)f2bf(f0.y);
        v[2] = (short)f2bf(f0.z); v[3] = (short)f2bf(f0.w);
        v[4] = (short)f2bf(f1.x); v[5] = (short)f2bf(f1.y);
        v[6] = (short)f2bf(f1.z); v[7] = (short)f2bf(f1.w);
    }
    *(short8*)(xb + (size_t)row * IN_PAD + c) = v;
}

// ---------- GEMM: C[M x 1024] = A[M x KP] * Bq[1024 x KP]^T ----------
// 256x256 tile, 8 waves (2m x 4n), BK=64. LDS: 2 K-tile ring, each {A 256x64,
// B 256x64} stored as st_16x32 subtiles (swizzle: granule g ^= (r16>=8)<<1).
// Staging: global_load_lds w=16, linear dest + pre-swizzled source granule.
// Per K-tile: 4 quadrant phases, 1 half-tile staged per phase, vmcnt(2) fence
// once per K-tile. Stage of tile t+1 at {P4(t-1),P1(t),P2(t),P3(t)} targets
// slots dead since {P3(t-1),P3(t-1),P4(t-1),P4(t-1)} -- verified safe.
template<int KP>
__global__ __launch_bounds__(512, 2)
void gemm_bt(const unsigned short* __restrict__ A, const unsigned short* __restrict__ Bq,
             unsigned short* __restrict__ C) {
    constexpr int NT = KP / 64;
    __shared__ __attribute__((aligned(16))) unsigned short LDS[65536];  // 128 KB
    const int tid = threadIdx.x;
    const int lane = tid & 63;
    const int w = tid >> 6;
    const int wm = w >> 2, wn = w & 3;
    const int lr = lane & 15, g0 = lane >> 4;
    const int gsw8 = (g0 ^ ((lr >> 3) << 1)) * 8;   // swizzled granule offset (shorts)
    const int lrO = lr * 32;
    // XCD-grouped bijective swizzle (grid = Mblks*4, Mblks % 8 == 0)
    const int bid = blockIdx.x;
    const int xcd = bid & 7, slot = bid >> 3;
    const int nblk = slot & 3;
    const int mblk = xcd * (gridDim.x >> 5) + (slot >> 2);
    const int m0 = mblk * 256, n0 = nblk * 256;
    // staging source (pre-swizzled) coords for this thread's two 16B granules
    int Dg = tid, s_ = Dg >> 6, r16 = (Dg >> 2) & 15, g = Dg & 3;
    const int r1 = (s_ >> 1) * 16 + r16;
    const int c1 = (s_ & 1) * 32 + (g ^ ((r16 >> 3) << 1)) * 8;
    Dg = tid + 512; s_ = Dg >> 6; r16 = (Dg >> 2) & 15; g = Dg & 3;
    const int r2 = (s_ >> 1) * 16 + r16;
    const int c2 = (s_ & 1) * 32 + (g ^ ((r16 >> 3) << 1)) * 8;
    const int wbs = w * 512;   // wave-uniform LDS dest base (shorts) per 8KB chunk

#define STAGE(gbase, ldsbase)                                                  \
    {   const unsigned short* _g = (gbase);                                    \
        unsigned short* _l = (ldsbase);                                        \
        GLOAD16(_g + (size_t)r1 * KP + c1, _l + wbs);                          \
        GLOAD16(_g + (size_t)r2 * KP + c2, _l + 4096 + wbs); }
#define STAGE_A(bi, h, t) STAGE(A + (size_t)(m0 + (h) * 128) * KP + (t) * 64,  \
                                &LDS[(bi) * 32768 + (h) * 8192])
#define STAGE_B(bi, h, t) STAGE(Bq + (size_t)(n0 + (h) * 128) * KP + (t) * 64, \
                                &LDS[(bi) * 32768 + 16384 + (h) * 8192])
#define LD_A(mq)                                                               \
    _Pragma("unroll") for (int mf = 0; mf < 4; ++mf)                           \
    _Pragma("unroll") for (int kk = 0; kk < 2; ++kk)                           \
        af[mf][kk] = *(const short8*)&LDS[curS +                               \
            ((wm * 8 + (mq) * 4 + mf) * 2 + kk) * 512 + lrO + gsw8];
#define LD_B(nq)                                                               \
    _Pragma("unroll") for (int nf = 0; nf < 2; ++nf)                           \
    _Pragma("unroll") for (int kk = 0; kk < 2; ++kk)                           \
        bf[nf][kk] = *(const short8*)&LDS[curS + 16384 +                       \
            ((wn * 4 + (nq) * 2 + nf) * 2 + kk) * 512 + lrO + gsw8];
#define QMM(mq, nq)                                                            \
    _Pragma("unroll") for (int kk = 0; kk < 2; ++kk)                           \
    _Pragma("unroll") for (int mf = 0; mf < 4; ++mf)                           \
    _Pragma("unroll") for (int nf = 0; nf < 2; ++nf)                           \
        acc[(mq) * 4 + mf][(nq) * 2 + nf] =                                    \
            __builtin_amdgcn_mfma_f32_16x16x32_bf16(af[mf][kk], bf[nf][kk],    \
                acc[(mq) * 4 + mf][(nq) * 2 + nf], 0, 0, 0);

    f32x4 acc[8][4] = {};
    short8 af[4][2], bf[2][2];
    // prologue: tile0 -> buf0 (4 halves), tile1 A-lo -> buf1
    STAGE_A(0, 0, 0); STAGE_A(0, 1, 0); STAGE_B(0, 0, 0); STAGE_B(0, 1, 0);
    STAGE_A(1, 0, 1);
    asm volatile("s_waitcnt vmcnt(2)" ::: "memory");   // tile0 complete
    BAR();
#pragma unroll 2
    for (int t = 0; t < NT; ++t) {
        const int cur = t & 1, nxt = cur ^ 1;
        const int curS = cur * 32768;
        // P1: Q(0,0) -- 12 ds_read; stage A-hi(t+1)
        LD_A(0); LD_B(0);
        if (t + 1 < NT) STAGE_A(nxt, 1, t + 1);
        BAR();
        __builtin_amdgcn_s_setprio(1); QMM(0, 0); __builtin_amdgcn_s_setprio(0);
        BAR();
        // P2: Q(0,1) -- stage B-lo(t+1)
        LD_B(1);
        if (t + 1 < NT) STAGE_B(nxt, 0, t + 1);
        BAR();
        __builtin_amdgcn_s_setprio(1); QMM(0, 1); __builtin_amdgcn_s_setprio(0);
        BAR();
        // P3: Q(1,1) -- stage B-hi(t+1)
        LD_A(1);
        if (t + 1 < NT) STAGE_B(nxt, 1, t + 1);
        BAR();
        __builtin_amdgcn_s_setprio(1); QMM(1, 1); __builtin_amdgcn_s_setprio(0);
        BAR();
        // P4: Q(1,0) -- stage A-lo(t+2) into cur (A slots dead after P3)
        LD_B(0);
        if (t + 2 < NT) STAGE_A(cur, 0, t + 2);
        BAR();
        __builtin_amdgcn_s_setprio(1); QMM(1, 0); __builtin_amdgcn_s_setprio(0);
        asm volatile("s_waitcnt vmcnt(2)" ::: "memory");  // tile t+1 landed
        BAR();
    }
    // epilogue: C/D layout col=lane&15, row=(lane>>4)*4+j (HW-verified)
#pragma unroll
    for (int mf = 0; mf < 8; ++mf) {
        const int grow = m0 + wm * 128 + mf * 16 + (lane >> 4) * 4;
#pragma unroll
        for (int nf = 0; nf < 4; ++nf) {
            const int gcol = n0 + wn * 64 + nf * 16 + lr;
            unsigned short* Cp = C + (size_t)grow * H_DIM + gcol;
#pragma unroll
            for (int j = 0; j < 4; ++j) Cp[(size_t)j * H_DIM] = f2bf(acc[mf][nf][j]);
        }
    }
#undef STAGE
#undef STAGE_A
#undef STAGE_B
#undef LD_A
#undef LD_B
#undef QMM
}

// ---------- rmsnorm + exact gelu, one wave per 1024-wide row ----------
__global__ __launch_bounds__(256)
void norm_gelu(const unsigned short* __restrict__ Hp, const float* __restrict__ g,
               unsigned short* __restrict__ U) {
    const int row = blockIdx.x * 4 + (threadIdx.x >> 6);
    const int lane = threadIdx.x & 63;
    const unsigned short* rp = Hp + (size_t)row * H_DIM;
    short8 v0 = *(const short8*)(rp + lane * 8);
    short8 v1 = *(const short8*)(rp + 512 + lane * 8);
    float f[16];
#pragma unroll
    for (int j = 0; j < 8; ++j) {
        f[j] = bf2f((unsigned short)v0[j]);
        f[8 + j] = bf2f((unsigned short)v1[j]);
    }
    float s = 0.f;
#pragma unroll
    for (int j = 0; j < 16; ++j) s += f[j] * f[j];
#pragma unroll
    for (int o = 32; o > 0; o >>= 1) s += __shfl_xor(s, o);
    const float rinv = 1.f / sqrtf(s * (1.f / 1024.f) + 1e-6f);
    short8 o0, o1;
#pragma unroll
    for (int j = 0; j < 8; ++j) {
        const int c0 = lane * 8 + j, c1 = 512 + lane * 8 + j;
        float t0 = f[j] * rinv * g[c0];
        float t1 = f[8 + j] * rinv * g[c1];
        float u0 = 0.5f * t0 * (1.f + erff(t0 * 0.70710678118f));
        float u1 = 0.5f * t1 * (1.f + erff(t1 * 0.70710678118f));
        o0[j] = (short)f2bf(u0);
        o1[j] = (short)f2bf(u1);
    }
    unsigned short* up = U + (size_t)row * H_DIM;
    *(short8*)(up + lane * 8) = o0;
    *(short8*)(up + 512 + lane * 8) = o1;
}

// ---------- final layer: out[M x 10] = A[M x 1024] * w3q[16 x 1024]^T ----------
__global__ __launch_bounds__(256)
void gemm3_kernel(const unsigned short* __restrict__ A, const unsigned short* __restrict__ Bq,
                  float* __restrict__ out) {
    __shared__ unsigned short As[128][40];
    __shared__ unsigned short Bs[16][40];
    const int tid = threadIdx.x;
    const int lane = tid & 63;
    const int wid = tid >> 6;
    const int m0 = blockIdx.x * 128;
    const int lr = lane & 15;
    const int lk = (lane >> 4) * 8;
    const int sr = tid >> 2;
    const int sc = (tid & 3) * 8;
    f32x4 acc[2] = {};
    for (int kt = 0; kt < 32; ++kt) {
        const int kb = kt * 32;
        __syncthreads();
#pragma unroll
        for (int p = 0; p < 2; ++p) {
            const int r = p * 64 + sr;
            *(short8*)&As[r][sc] = *(const short8*)(A + (size_t)(m0 + r) * H_DIM + kb + sc);
        }
        if (tid < 64) {
            const int r = tid >> 2;
            const int c = (tid & 3) * 8;
            *(short8*)&Bs[r][c] = *(const short8*)(Bq + (size_t)r * H_DIM + kb + c);
        }
        __syncthreads();
        short8 bv = *(const short8*)&Bs[lr][lk];
#pragma unroll
        for (int m = 0; m < 2; ++m) {
            short8 a = *(const short8*)&As[wid * 32 + m * 16 + lr][lk];
            acc[m] = __builtin_amdgcn_mfma_f32_16x16x32_bf16(a, bv, acc[m], 0, 0, 0);
        }
    }
    if (lr < OUT_DIM) {
#pragma unroll
        for (int m = 0; m < 2; ++m)
#pragma unroll
            for (int j = 0; j < 4; ++j) {
                const int grow = m0 + wid * 32 + m * 16 + (lane >> 4) * 4 + j;
                out[(size_t)grow * OUT_DIM + lr] = acc[m][j];
            }
    }
}

extern "C" void kernel_launch(void* const* d_in, const int* in_sizes, int n_in,
                              void* d_out, int out_size, void* d_ws, size_t ws_size,
                              hipStream_t stream) {
    (void)in_sizes; (void)n_in; (void)out_size;
    const float* x  = (const float*)d_in[0];
    const float* w1 = (const float*)d_in[1];
    const float* g1 = (const float*)d_in[2];
    const float* w2 = (const float*)d_in[3];
    const float* g2 = (const float*)d_in[4];
    const float* w3 = (const float*)d_in[5];
    float* out = (float*)d_out;

    uint8_t* ws = (uint8_t*)d_ws;
    double* sums = (double*)ws;
    size_t off = 256;
    unsigned short* w1q = (unsigned short*)(ws + off); off += (size_t)H_DIM * IN_PAD * 2;
    unsigned short* w2q = (unsigned short*)(ws + off); off += (size_t)H_DIM * H_DIM * 2;
    unsigned short* w3q = (unsigned short*)(ws + off); off += (size_t)OUT_PAD * H_DIM * 2;

    // largest pow2 chunk R (multiple of 2048 for the 256-tile XCD swizzle) whose
    // two bf16 [R x 1024] buffers fit; bufB doubles as the bf16 x-chunk [R x 896]
    size_t rem = (ws_size > off) ? ws_size - off : 0;
    int R = B_TOTAL;
    while (R > 2048 && (size_t)2 * R * H_DIM * 2 > rem) R >>= 1;
    unsigned short* bufA = (unsigned short*)(ws + off);
    unsigned short* bufB = bufA + (size_t)R * H_DIM;

    hipMemsetAsync(sums, 0, 3 * sizeof(double), stream);
    absum_kernel<<<128, 256, 0, stream>>>(w1, H_DIM * IN_DIM, sums + 0);
    absum_kernel<<<128, 256, 0, stream>>>(w2, H_DIM * H_DIM, sums + 1);
    absum_kernel<<<128, 256, 0, stream>>>(w3, OUT_DIM * H_DIM, sums + 2);
    quant_kernel<<<dim3((IN_PAD + 255) / 256, H_DIM), 256, 0, stream>>>(
        w1, w1q, H_DIM, IN_DIM, IN_PAD, sums + 0, H_DIM * IN_DIM);
    quant_kernel<<<dim3((H_DIM + 255) / 256, H_DIM), 256, 0, stream>>>(
        w2, w2q, H_DIM, H_DIM, H_DIM, sums + 1, H_DIM * H_DIM);
    quant_kernel<<<dim3((H_DIM + 255) / 256, OUT_PAD), 256, 0, stream>>>(
        w3, w3q, OUT_DIM, H_DIM, H_DIM, sums + 2, OUT_DIM * H_DIM);

    const int nchunk = B_TOTAL / R;
    for (int c = 0; c < nchunk; ++c) {
        const float* xc = x + (size_t)c * R * IN_DIM;
        convert_pad<<<R * 112 / 256, 256, 0, stream>>>(xc, bufB);
        gemm_bt<IN_PAD><<<(R / 256) * 4, 512, 0, stream>>>(bufB, w1q, bufA);
        norm_gelu<<<R / 4, 256, 0, stream>>>(bufA, g1, bufB);
        gemm_bt<H_DIM><<<(R / 256) * 4, 512, 0, stream>>>(bufB, w2q, bufA);
        norm_gelu<<<R / 4, 256, 0, stream>>>(bufA, g2, bufB);
        gemm3_kernel<<<R / 128, 256, 0, stream>>>(bufB, w3q, out + (size_t)c * R * OUT_DIM);
    }
}

// Round 5
// 631.322 us; speedup vs baseline: 1.3993x; 1.0007x over previous
//
#include <hip/hip_runtime.h>
#include <hip/hip_bf16.h>
#include <stdint.h>

// BitNet MNIST MLP, Round 4: 256x256 4-phase GEMM, deep pipeline (vmcnt(6))
// with staging granules partitioned by ACTUAL read-group lifetimes:
//   A-g0 (slots {0-7,16-23})   read @P1 only -> stage into cur @P2
//   B-nq1 (slots {4-7,12-15}+16) read @P2 only -> stage into cur @P3
//   A-g1 (slots {8-15,24-31})  read @P3 only -> stage into cur @P4
//   B-nq0 (slots {0-3,8-11}+16) read @P1,P4  -> stage into nxt @P1
// (Round 3 raced: lo/hi 128-row halves do NOT match quadrant read sets.)

typedef __attribute__((ext_vector_type(8))) short short8;
typedef __attribute__((ext_vector_type(4))) float f32x4;

#define B_TOTAL 65536
#define IN_DIM 784
#define IN_PAD 896
#define H_DIM 1024
#define OUT_DIM 10
#define OUT_PAD 16

__device__ __forceinline__ unsigned short f2bf(float f) {
    union { float f; unsigned u; } c; c.f = f;
    unsigned r = c.u + 0x7FFFu + ((c.u >> 16) & 1u);
    return (unsigned short)(r >> 16);
}
__device__ __forceinline__ float bf2f(unsigned short h) {
    union { unsigned u; float f; } c; c.u = ((unsigned)h) << 16;
    return c.f;
}

#define GLOAD16(gp, lp)                                                        \
    __builtin_amdgcn_global_load_lds(                                          \
        (const __attribute__((address_space(1))) void*)(gp),                   \
        (__attribute__((address_space(3))) void*)(lp), 16, 0, 0)

#define BAR()                                                                  \
    {   __builtin_amdgcn_sched_barrier(0);                                     \
        __builtin_amdgcn_s_barrier();                                          \
        __builtin_amdgcn_sched_barrier(0); }

// ---------- weight |w| sum (double atomic: deterministic) ----------
__global__ void absum_kernel(const float* __restrict__ w, int n, double* acc) {
    __shared__ float red[4];
    float s = 0.f;
    for (int i = blockIdx.x * blockDim.x + threadIdx.x; i < n; i += gridDim.x * blockDim.x)
        s += fabsf(w[i]);
#pragma unroll
    for (int o = 32; o > 0; o >>= 1) s += __shfl_xor(s, o);
    if ((threadIdx.x & 63) == 0) red[threadIdx.x >> 6] = s;
    __syncthreads();
    if (threadIdx.x == 0) {
        float t = red[0] + red[1] + red[2] + red[3];
        atomicAdd(acc, (double)t);
    }
}

// ---------- ternary quantize -> bf16, pad K to Kp and O rows up ----------
__global__ void quant_kernel(const float* __restrict__ w, unsigned short* __restrict__ wq,
                             int O, int K, int Kp, const double* sum, int n) {
    int k = blockIdx.x * blockDim.x + threadIdx.x;
    int o = blockIdx.y;
    if (k >= Kp) return;
    float scale = fmaxf((float)(*sum / (double)n), 1e-5f);
    float q = 0.f;
    if (o < O && k < K) {
        float r = rintf(w[(size_t)o * K + k] / scale);  // round-half-even == jnp.round
        q = fminf(1.f, fmaxf(-1.f, r));
    }
    wq[(size_t)o * Kp + k] = f2bf(q);
}

// ---------- x fp32 [R x 784] -> bf16 [R x 896] (zero-padded) ----------
__global__ __launch_bounds__(256)
void convert_pad(const float* __restrict__ x, unsigned short* __restrict__ xb) {
    const int g = blockIdx.x * 256 + threadIdx.x;   // one 8-col group per thread
    const int row = g / 112;
    const int c = (g % 112) * 8;
    short8 v = 0;
    if (c < IN_DIM) {
        const float* p = x + (size_t)row * IN_DIM + c;
        float4 f0 = *(const float4*)p;
        float4 f1 = *(const float4*)(p + 4);
        v[0] = (short)f2bf(f0.x); v[1] = (short)f2bf(f0.y);
        v[2] = (short)f2bf(f0.z); v[3] = (short)f2bf(f0.w);
        v[4] = (short)f2bf(f1.x); v[5] = (short)f2bf(f1.y);
        v[6] = (short)f2bf(f1.z); v[7] = (short)f2bf(f1.w);
    }
    *(short8*)(xb + (size_t)row * IN_PAD + c) = v;
}

// ---------- GEMM: C[M x 1024] = A[M x KP] * Bq[1024 x KP]^T ----------
// 256x256 tile, 8 waves (2m x 4n), BK=64, 2 K-tile LDS ring, st_16x32 swizzle.
// Slot = 1KB block (16 rows x 32 cols), index st = rowsubtile*2 + kk (0..31).
// Per-iter stages: P1 B-nq0(t+1)->nxt, P2 A-g0(t+2)->cur, P3 B-nq1(t+2)->cur,
// P4 A-g1(t+2)->cur; each target group's last read completed one barrier +
// one lgkm-drained QMM region earlier (verified per-group). Fence vmcnt(6)
// per K-tile (steady 14 loads in flight, drain 8 = tile t+1); vmcnt(0) at
// t==NT-2 (tail stages skipped).
template<int KP>
__global__ __launch_bounds__(512, 2)
void gemm_bt(const unsigned short* __restrict__ A, const unsigned short* __restrict__ Bq,
             unsigned short* __restrict__ C) {
    constexpr int NT = KP / 64;
    __shared__ __attribute__((aligned(16))) unsigned short LDS[65536];  // 128 KB
    const int tid = threadIdx.x;
    const int lane = tid & 63;
    const int w = tid >> 6;
    const int wm = w >> 2, wn = w & 3;
    const int lr = lane & 15, gq = lane >> 4;
    const int gsw8 = (gq ^ ((lr >> 3) << 1)) * 8;   // swizzled granule offset (shorts)
    const int lrO = lr * 32;
    // XCD-grouped bijective swizzle (grid = Mblks*4, Mblks % 8 == 0)
    const int bid = blockIdx.x;
    const int xcd = bid & 7, slot = bid >> 3;
    const int nblk = slot & 3;
    const int mblk = xcd * (gridDim.x >> 5) + (slot >> 2);
    const int m0 = mblk * 256, n0 = nblk * 256;
    // staging source coords (pre-swizzled involution, same as verified r2 kernel)
    const int rS = lane >> 2;                            // row within 16-row subtile
    const int cS = ((lane & 3) ^ ((lane >> 5) << 1)) * 8;  // swizzled col granule
    // per-wave slot assignments (wave w stages slots st and st+16 of a group)
    const int stA0 = w;                          // A-g0: read @P1 (LD_A(0))
    const int stA1 = 8 + w;                      // A-g1: read @P3 (LD_A(1))
    const int stB_P1 = (w >> 2) * 8 + (w & 3);   // B-nq0: read @P1,P4 (LD_B(0))
    const int stB_P3 = stB_P1 + 4;               // B-nq1: read @P2 (LD_B(1))

// stage one 16-slot group (16 KB): wave w covers slots {st, st+16};
// slot st -> global rows [(st>>1)*16, +16), cols [(st&1)*32, +32); +16 slots = +128 rows
#define STG(gbase, areaS, st)                                                  \
    {   const unsigned short* _g = (gbase) +                                   \
            (size_t)(((st) >> 1) * 16 + rS) * KP + ((st) & 1) * 32 + cS;       \
        GLOAD16(_g, &LDS[(areaS) + (st) * 512]);                               \
        GLOAD16(_g + (size_t)128 * KP, &LDS[(areaS) + (st) * 512 + 8192]); }
#define ABASE(t) (A + (size_t)m0 * KP + (t) * 64)
#define BBASE(t) (Bq + (size_t)n0 * KP + (t) * 64)
#define LD_A(mq)                                                               \
    _Pragma("unroll") for (int mf = 0; mf < 4; ++mf)                           \
    _Pragma("unroll") for (int kk = 0; kk < 2; ++kk)                           \
        af[mf][kk] = *(const short8*)&LDS[curS +                               \
            ((wm * 8 + (mq) * 4 + mf) * 2 + kk) * 512 + lrO + gsw8];
#define LD_B(nq)                                                               \
    _Pragma("unroll") for (int nf = 0; nf < 2; ++nf)                           \
    _Pragma("unroll") for (int kk = 0; kk < 2; ++kk)                           \
        bf[nf][kk] = *(const short8*)&LDS[curS + 16384 +                       \
            ((wn * 4 + (nq) * 2 + nf) * 2 + kk) * 512 + lrO + gsw8];
#define QMM(mq, nq)                                                            \
    _Pragma("unroll") for (int kk = 0; kk < 2; ++kk)                           \
    _Pragma("unroll") for (int mf = 0; mf < 4; ++mf)                           \
    _Pragma("unroll") for (int nf = 0; nf < 2; ++nf)                           \
        acc[(mq) * 4 + mf][(nq) * 2 + nf] =                                    \
            __builtin_amdgcn_mfma_f32_16x16x32_bf16(af[mf][kk], bf[nf][kk],    \
                acc[(mq) * 4 + mf][(nq) * 2 + nf], 0, 0, 0);

    f32x4 acc[8][4] = {};
    short8 af[4][2], bf[2][2];
    // prologue: tile0 all 4 groups -> buf0 (8 loads), then tile1 {A-g0, B-nq1,
    // A-g1} -> buf1 (6 loads, steady-state P2/P3/P4 order). vmcnt(6) = tile0 done.
    STG(ABASE(0), 0, stA0);       STG(ABASE(0), 0, stA1);
    STG(BBASE(0), 16384, stB_P1); STG(BBASE(0), 16384, stB_P3);
    STG(ABASE(1), 32768, stA0);
    STG(BBASE(1), 32768 + 16384, stB_P3);
    STG(ABASE(1), 32768, stA1);
    __builtin_amdgcn_sched_barrier(0);
    asm volatile("s_waitcnt vmcnt(6)" ::: "memory");   // tile0 complete
    BAR();
#pragma unroll 2
    for (int t = 0; t < NT; ++t) {
        const int cur = t & 1, nxt = cur ^ 1;
        const int curS = cur * 32768;
        // P1: Q(0,0); stage B-nq0(t+1) -> nxt (nxt's B-nq0 died @P4(t-1))
        LD_A(0); LD_B(0);
        if (t + 1 < NT) STG(BBASE(t + 1), nxt * 32768 + 16384, stB_P1);
        BAR();
        __builtin_amdgcn_s_setprio(1); QMM(0, 0); __builtin_amdgcn_s_setprio(0);
        BAR();
        // P2: Q(0,1); stage A-g0(t+2) -> cur (A-g0(t) died @P1)
        LD_B(1);
        if (t + 2 < NT) STG(ABASE(t + 2), curS, stA0);
        BAR();
        __builtin_amdgcn_s_setprio(1); QMM(0, 1); __builtin_amdgcn_s_setprio(0);
        BAR();
        // P3: Q(1,1); stage B-nq1(t+2) -> cur (B-nq1(t) died @P2)
        LD_A(1);
        if (t + 2 < NT) STG(BBASE(t + 2), curS + 16384, stB_P3);
        BAR();
        __builtin_amdgcn_s_setprio(1); QMM(1, 1); __builtin_amdgcn_s_setprio(0);
        BAR();
        // P4: Q(1,0); stage A-g1(t+2) -> cur (A-g1(t) died @P3)
        LD_B(0);
        if (t + 2 < NT) STG(ABASE(t + 2), curS, stA1);
        BAR();
        __builtin_amdgcn_s_setprio(1); QMM(1, 0); __builtin_amdgcn_s_setprio(0);
        __builtin_amdgcn_sched_barrier(0);
        // fence: tile t+1 fully landed; tile t+2's 3 groups stay in flight
        if (t < NT - 2) {
            asm volatile("s_waitcnt vmcnt(6)" ::: "memory");
        } else if (t == NT - 2) {
            asm volatile("s_waitcnt vmcnt(0)" ::: "memory");
        }
        BAR();
    }
    // epilogue: C/D layout col=lane&15, row=(lane>>4)*4+j (HW-verified)
#pragma unroll
    for (int mf = 0; mf < 8; ++mf) {
        const int grow = m0 + wm * 128 + mf * 16 + (lane >> 4) * 4;
#pragma unroll
        for (int nf = 0; nf < 4; ++nf) {
            const int gcol = n0 + wn * 64 + nf * 16 + lr;
            unsigned short* Cp = C + (size_t)grow * H_DIM + gcol;
#pragma unroll
            for (int j = 0; j < 4; ++j) Cp[(size_t)j * H_DIM] = f2bf(acc[mf][nf][j]);
        }
    }
#undef STG
#undef ABASE
#undef BBASE
#undef LD_A
#undef LD_B
#undef QMM
}

// ---------- rmsnorm + exact gelu, one wave per 1024-wide row ----------
__global__ __launch_bounds__(256)
void norm_gelu(const unsigned short* __restrict__ Hp, const float* __restrict__ g,
               unsigned short* __restrict__ U) {
    const int row = blockIdx.x * 4 + (threadIdx.x >> 6);
    const int lane = threadIdx.x & 63;
    const unsigned short* rp = Hp + (size_t)row * H_DIM;
    short8 v0 = *(const short8*)(rp + lane * 8);
    short8 v1 = *(const short8*)(rp + 512 + lane * 8);
    float f[16];
#pragma unroll
    for (int j = 0; j < 8; ++j) {
        f[j] = bf2f((unsigned short)v0[j]);
        f[8 + j] = bf2f((unsigned short)v1[j]);
    }
    float s = 0.f;
#pragma unroll
    for (int j = 0; j < 16; ++j) s += f[j] * f[j];
#pragma unroll
    for (int o = 32; o > 0; o >>= 1) s += __shfl_xor(s, o);
    const float rinv = 1.f / sqrtf(s * (1.f / 1024.f) + 1e-6f);
    short8 o0, o1;
#pragma unroll
    for (int j = 0; j < 8; ++j) {
        const int c0 = lane * 8 + j, c1 = 512 + lane * 8 + j;
        float t0 = f[j] * rinv * g[c0];
        float t1 = f[8 + j] * rinv * g[c1];
        float u0 = 0.5f * t0 * (1.f + erff(t0 * 0.70710678118f));
        float u1 = 0.5f * t1 * (1.f + erff(t1 * 0.70710678118f));
        o0[j] = (short)f2bf(u0);
        o1[j] = (short)f2bf(u1);
    }
    unsigned short* up = U + (size_t)row * H_DIM;
    *(short8*)(up + lane * 8) = o0;
    *(short8*)(up + 512 + lane * 8) = o1;
}

// ---------- final layer: out[M x 10] = A[M x 1024] * w3q[16 x 1024]^T ----------
__global__ __launch_bounds__(256)
void gemm3_kernel(const unsigned short* __restrict__ A, const unsigned short* __restrict__ Bq,
                  float* __restrict__ out) {
    __shared__ unsigned short As[128][40];
    __shared__ unsigned short Bs[16][40];
    const int tid = threadIdx.x;
    const int lane = tid & 63;
    const int wid = tid >> 6;
    const int m0 = blockIdx.x * 128;
    const int lr = lane & 15;
    const int lk = (lane >> 4) * 8;
    const int sr = tid >> 2;
    const int sc = (tid & 3) * 8;
    f32x4 acc[2] = {};
    for (int kt = 0; kt < 32; ++kt) {
        const int kb = kt * 32;
        __syncthreads();
#pragma unroll
        for (int p = 0; p < 2; ++p) {
            const int r = p * 64 + sr;
            *(short8*)&As[r][sc] = *(const short8*)(A + (size_t)(m0 + r) * H_DIM + kb + sc);
        }
        if (tid < 64) {
            const int r = tid >> 2;
            const int c = (tid & 3) * 8;
            *(short8*)&Bs[r][c] = *(const short8*)(Bq + (size_t)r * H_DIM + kb + c);
        }
        __syncthreads();
        short8 bv = *(const short8*)&Bs[lr][lk];
#pragma unroll
        for (int m = 0; m < 2; ++m) {
            short8 a = *(const short8*)&As[wid * 32 + m * 16 + lr][lk];
            acc[m] = __builtin_amdgcn_mfma_f32_16x16x32_bf16(a, bv, acc[m], 0, 0, 0);
        }
    }
    if (lr < OUT_DIM) {
#pragma unroll
        for (int m = 0; m < 2; ++m)
#pragma unroll
            for (int j = 0; j < 4; ++j) {
                const int grow = m0 + wid * 32 + m * 16 + (lane >> 4) * 4 + j;
                out[(size_t)grow * OUT_DIM + lr] = acc[m][j];
            }
    }
}

extern "C" void kernel_launch(void* const* d_in, const int* in_sizes, int n_in,
                              void* d_out, int out_size, void* d_ws, size_t ws_size,
                              hipStream_t stream) {
    (void)in_sizes; (void)n_in; (void)out_size;
    const float* x  = (const float*)d_in[0];
    const float* w1 = (const float*)d_in[1];
    const float* g1 = (const float*)d_in[2];
    const float* w2 = (const float*)d_in[3];
    const float* g2 = (const float*)d_in[4];
    const float* w3 = (const float*)d_in[5];
    float* out = (float*)d_out;

    uint8_t* ws = (uint8_t*)d_ws;
    double* sums = (double*)ws;
    size_t off = 256;
    unsigned short* w1q = (unsigned short*)(ws + off); off += (size_t)H_DIM * IN_PAD * 2;
    unsigned short* w2q = (unsigned short*)(ws + off); off += (size_t)H_DIM * H_DIM * 2;
    unsigned short* w3q = (unsigned short*)(ws + off); off += (size_t)OUT_PAD * H_DIM * 2;

    // largest pow2 chunk R (multiple of 2048 for the 256-tile XCD swizzle) whose
    // two bf16 [R x 1024] buffers fit; bufB doubles as the bf16 x-chunk [R x 896]
    size_t rem = (ws_size > off) ? ws_size - off : 0;
    int R = B_TOTAL;
    while (R > 2048 && (size_t)2 * R * H_DIM * 2 > rem) R >>= 1;
    unsigned short* bufA = (unsigned short*)(ws + off);
    unsigned short* bufB = bufA + (size_t)R * H_DIM;

    hipMemsetAsync(sums, 0, 3 * sizeof(double), stream);
    absum_kernel<<<128, 256, 0, stream>>>(w1, H_DIM * IN_DIM, sums + 0);
    absum_kernel<<<128, 256, 0, stream>>>(w2, H_DIM * H_DIM, sums + 1);
    absum_kernel<<<128, 256, 0, stream>>>(w3, OUT_DIM * H_DIM, sums + 2);
    quant_kernel<<<dim3((IN_PAD + 255) / 256, H_DIM), 256, 0, stream>>>(
        w1, w1q, H_DIM, IN_DIM, IN_PAD, sums + 0, H_DIM * IN_DIM);
    quant_kernel<<<dim3((H_DIM + 255) / 256, H_DIM), 256, 0, stream>>>(
        w2, w2q, H_DIM, H_DIM, H_DIM, sums + 1, H_DIM * H_DIM);
    quant_kernel<<<dim3((H_DIM + 255) / 256, OUT_PAD), 256, 0, stream>>>(
        w3, w3q, OUT_DIM, H_DIM, H_DIM, sums + 2, OUT_DIM * H_DIM);

    const int nchunk = B_TOTAL / R;
    for (int c = 0; c < nchunk; ++c) {
        const float* xc = x + (size_t)c * R * IN_DIM;
        convert_pad<<<R * 112 / 256, 256, 0, stream>>>(xc, bufB);
        gemm_bt<IN_PAD><<<(R / 256) * 4, 512, 0, stream>>>(bufB, w1q, bufA);
        norm_gelu<<<R / 4, 256, 0, stream>>>(bufA, g1, bufB);
        gemm_bt<H_DIM><<<(R / 256) * 4, 512, 0, stream>>>(bufB, w2q, bufA);
        norm_gelu<<<R / 4, 256, 0, stream>>>(bufA, g2, bufB);
        gemm3_kernel<<<R / 128, 256, 0, stream>>>(bufB, w3q, out + (size_t)c * R * OUT_DIM);
    }
}